// Round 4
// baseline (1286.811 us; speedup 1.0000x reference)
//
#include <hip/hip_runtime.h>

#define DD 1024
#define FF 4096
#define LL 24
#define VV 50277
#define NB 1024
#define SCOPE __HIP_MEMORY_SCOPE_AGENT

typedef unsigned u32;
typedef float v4f __attribute__((ext_vector_type(4)));

// ---------------- reductions ----------------

__device__ __forceinline__ float wave_sum(float v) {
#pragma unroll
    for (int o = 32; o > 0; o >>= 1) v += __shfl_xor(v, o, 64);
    return v;
}

__device__ __forceinline__ float block_sum(float v, float* scr) {
    v = wave_sum(v);
    int w = threadIdx.x >> 6;
    __syncthreads();                    // protect scr from previous use
    if ((threadIdx.x & 63) == 0) scr[w] = v;
    __syncthreads();
    return scr[0] + scr[1] + scr[2] + scr[3];
}

__device__ __forceinline__ v4f ln_vec(v4f xv, const float* __restrict__ w,
                                      const float* __restrict__ b, float* scr, int t) {
    float m = block_sum(xv[0] + xv[1] + xv[2] + xv[3], scr) * (1.0f / 1024.0f);
    v4f d = xv - m;
    float var = block_sum(d[0]*d[0] + d[1]*d[1] + d[2]*d[2] + d[3]*d[3], scr) * (1.0f / 1024.0f);
    float rs = rsqrtf(var + 1e-5f);
    v4f w4 = ((const v4f*)w)[t], b4 = ((const v4f*)b)[t];
    return d * rs * w4 + b4;
}

__device__ __forceinline__ v4f mixv(v4f n, v4f s, v4f m) { return n * m + s * (1.0f - m); }

__device__ __forceinline__ float dotv(v4f a, v4f x) {
    return fmaf(a[0], x[0], fmaf(a[1], x[1], fmaf(a[2], x[2], a[3] * x[3])));
}

// ---------------- weight row in 16 VGPRs ----------------

struct Row { v4f a, b, c, d; };

__device__ __forceinline__ void row_load(Row& r, const float* p, int lane) {
    const v4f* q = (const v4f*)p;
    r.a = q[lane]; r.b = q[lane + 64]; r.c = q[lane + 128]; r.d = q[lane + 192];
}
__device__ __forceinline__ void row_pin(Row& r) {      // force loads issued here
    asm volatile("" : "+v"(r.a), "+v"(r.b), "+v"(r.c), "+v"(r.d));
}
__device__ __forceinline__ float row_dot(const Row& r, const v4f* v, int lane) {
    return dotv(r.a, v[lane]) + dotv(r.b, v[lane + 64]) +
           dotv(r.c, v[lane + 128]) + dotv(r.d, v[lane + 192]);
}

// ---------------- coherent (LLC) ops: fenceless relaxed agent scope ----------

__device__ __forceinline__ void astore_f(float* p, float v) {
    __hip_atomic_store(p, v, __ATOMIC_RELAXED, SCOPE);
}
// coherent 16B load: sc0 sc1 bypass non-coherent caches; wait is data-tied
__device__ __forceinline__ void cload(v4f& d, const float* p) {
    asm volatile("global_load_dwordx4 %0, %1, off sc0 sc1" : "=v"(d) : "v"(p));
}
__device__ __forceinline__ void cwait1(v4f& a) {
    asm volatile("s_waitcnt vmcnt(0)" : "+v"(a));
}
__device__ __forceinline__ void cwait3(v4f& a, v4f& b, v4f& c) {
    asm volatile("s_waitcnt vmcnt(0)" : "+v"(a), "+v"(b), "+v"(c));
}
__device__ __forceinline__ void cwait4(v4f& a, v4f& b, v4f& c, v4f& d) {
    asm volatile("s_waitcnt vmcnt(0)" : "+v"(a), "+v"(b), "+v"(c), "+v"(d));
}

// ---------------- leader-release grid barrier ----------------
// ctr: 32 shard lines (128B stride) — written by arrivals, read ONLY by block 0.
// rel: 8 release lines — written by block 0, polled by everyone else.

__device__ __forceinline__ void bar_arrive(u32* ctr, int b) {
    __syncthreads();   // per-wave vmcnt(0) drain: publishes retired to LLC first
    if (threadIdx.x == 0)
        __hip_atomic_fetch_add(&ctr[(b & 31) * 32], 1u, __ATOMIC_RELAXED, SCOPE);
}

__device__ __forceinline__ void bar_sync(u32* ctr, u32* rel, u32 ev1, int b) {
    if (threadIdx.x == 0) {
        if (b == 0) {
            const u32 target = ev1 * (u32)NB;
            for (;;) {
                u32 s = 0;
#pragma unroll
                for (int i = 0; i < 32; ++i)
                    s += __hip_atomic_load(&ctr[i * 32], __ATOMIC_RELAXED, SCOPE);
                if (s >= target) break;
                __builtin_amdgcn_s_sleep(2);
            }
#pragma unroll
            for (int i = 0; i < 8; ++i)
                __hip_atomic_store(&rel[i * 32], ev1, __ATOMIC_RELAXED, SCOPE);
        } else {
            while (__hip_atomic_load(&rel[(b & 7) * 32], __ATOMIC_RELAXED, SCOPE) < ev1)
                __builtin_amdgcn_s_sleep(16);
        }
    }
    __syncthreads();
}

// ---------------- the whole network, one kernel ----------------
// 1024 blocks x 256 threads, 4 blocks/CU (exact residency).
// Block b owns: channel b of kw/vw/rw/ow/fvw/frw outputs, rows 4b..4b+3 of fkw.

__global__ __launch_bounds__(256, 4) void rwkv_all(
    const float* __restrict__ token_embd, const float* __restrict__ state,
    const float* __restrict__ emb_ln_w, const float* __restrict__ emb_ln_b,
    const float* __restrict__ ln1_w, const float* __restrict__ ln1_b,
    const float* __restrict__ ln2_w, const float* __restrict__ ln2_b,
    const float* __restrict__ att_tmk, const float* __restrict__ att_tmv,
    const float* __restrict__ att_tmr, const float* __restrict__ att_tf,
    const float* __restrict__ att_td,
    const float* __restrict__ att_kw, const float* __restrict__ att_vw,
    const float* __restrict__ att_rw, const float* __restrict__ att_ow,
    const float* __restrict__ ffn_tmk, const float* __restrict__ ffn_tmr,
    const float* __restrict__ ffn_kw, const float* __restrict__ ffn_vw,
    const float* __restrict__ ffn_rw,
    const float* __restrict__ out_ln_w, const float* __restrict__ out_ln_b,
    const float* __restrict__ head_w,
    float* __restrict__ logits, float* __restrict__ st_out_base,
    float* __restrict__ ws, u32* __restrict__ syncm) {

    __shared__ v4f s_mix[3][256];   // xk/xv/xr ; xk2/xr2
    __shared__ v4f s_x4[256];       // current residual-stream x (full vector)
    __shared__ v4f s_vec[256];      // rab / head xn
    __shared__ float scr[4];
    __shared__ float s_red[8];

    const int t = threadIdx.x, lane = t & 63, w = t >> 6, b = blockIdx.x;

    float* xD = ws;                 // x after full layer   (1024)
    float* xB = ws + 1024;          // x after time-mixing  (1024)
    float* kk = ws + 2048;
    float* vv = ws + 3072;
    float* rr = ws + 4096;
    float* k2 = ws + 5120;          // 4096
    u32* ctr = syncm;               // 32 shards * 32-u32 stride
    u32* rel = syncm + 1024;        // 8 lines  * 32-u32 stride

    // ---- encoder: x0 = LN(token_embd), redundant per block ----
    v4f xcur = ((const v4f*)token_embd)[t];
    xcur = ln_vec(xcur, emb_ln_w, emb_ln_b, scr, t);

    // ---- prefetch layer-0 stage-A/B rows: waves 0-2 = kvr[b], wave 3 = ow[b]
    Row rAB;
    row_load(rAB, (w == 0 ? att_kw : w == 1 ? att_vw : w == 2 ? att_rw : att_ow)
                  + (size_t)b * DD, lane);

    u32 ev = 0;
#pragma unroll 1
    for (int i = 0; i < LL; ++i) {
        const size_t oD = (size_t)i * DD;
        const float* st = state + (size_t)i * 5 * DD;
        float* sto = st_out_base + (size_t)i * 5 * DD;
        const float scale = ((i + 1) % 6 == 0) ? 0.5f : 1.0f;

        // ================= stage A: LN1 + time-mix + {k,v,r} dots ==========
        v4f xv;
        if (i == 0) xv = xcur;
        else { cload(xv, xD + 4 * t); cwait1(xv); }
        s_x4[t] = xv;
        v4f n = ln_vec(xv, ln1_w + oD, ln1_b + oD, scr, t);
        if (b < 256 && t == b) {            // new_st[1] = xn (channels 4b..4b+3)
            float* p = sto + DD + 4 * b;
            p[0] = n[0]; p[1] = n[1]; p[2] = n[2]; p[3] = n[3];
        }
        {
            v4f sa = ((const v4f*)(st + DD))[t];
            s_mix[0][t] = mixv(n, sa, ((const v4f*)(att_tmk + oD))[t]);
            s_mix[1][t] = mixv(n, sa, ((const v4f*)(att_tmv + oD))[t]);
            s_mix[2][t] = mixv(n, sa, ((const v4f*)(att_tmr + oD))[t]);
        }
        __syncthreads();
        if (w < 3) {
            float acc = wave_sum(row_dot(rAB, &s_mix[w][0], lane));
            if (lane == 0) {
                if (w == 0)      astore_f(kk + b, acc);
                else if (w == 1) astore_f(vv + b, acc);
                else             astore_f(rr + b, 1.0f / (1.0f + expf(-acc)));
            }
        }
        // ---- B1 (prefetch fkw row 4b+w + frw quarter during the wait) ----
        bar_arrive(ctr, b);
        __builtin_amdgcn_sched_barrier(0);
        Row rFK;
        row_load(rFK, ffn_kw + (size_t)i * FF * DD + (size_t)(4 * b + w) * DD, lane);
        v4f fr4 = ((const v4f*)(ffn_rw + (size_t)i * DD * DD + (size_t)b * DD))[w * 64 + lane];
        row_pin(rFK);
        asm volatile("" : "+v"(fr4));
        bar_sync(ctr, rel, ++ev, b);

        // ================= stage B: wkv + ow dot + residual =================
        {
            v4f kx, vx, rx;
            cload(kx, kk + 4 * t); cload(vx, vv + 4 * t); cload(rx, rr + 4 * t);
            cwait3(kx, vx, rx);
            v4f aa = ((const v4f*)(st + 2 * DD))[t];
            v4f bb = ((const v4f*)(st + 3 * DD))[t];
            v4f pp = ((const v4f*)(st + 4 * DD))[t];
            v4f tf = ((const v4f*)(att_tf + oD))[t];
            v4f td = ((const v4f*)(att_td + oD))[t];
            v4f rab, naa, nbb, np2;
#pragma unroll
            for (int c = 0; c < 4; ++c) {
                float kc = kx[c], vc = vx[c];
                float wwc = tf[c] + kc;
                float p = fmaxf(pp[c], wwc);
                float e1 = expf(pp[c] - p), e2 = expf(wwc - p);
                rab[c] = rx[c] * ((e1 * aa[c] + e2 * vc) / (e1 * bb[c] + e2));
                float ww2 = pp[c] + td[c];
                float p2 = fmaxf(ww2, kc);
                float f1 = expf(ww2 - p2), f2 = expf(kc - p2);
                naa[c] = f1 * aa[c] + f2 * vc;
                nbb[c] = f1 * bb[c] + f2;
                np2[c] = p2;
            }
            s_vec[t] = rab;
            if (b < 256 && t == b) {
                float* pa = sto + 2 * DD + 4 * b;
                float* pb = sto + 3 * DD + 4 * b;
                float* pc = sto + 4 * DD + 4 * b;
#pragma unroll
                for (int c = 0; c < 4; ++c) { pa[c] = naa[c]; pb[c] = nbb[c]; pc[c] = np2[c]; }
            }
        }
        __syncthreads();
        if (w == 3) {               // ow row is in rAB (wave 3)
            float acc = wave_sum(row_dot(rAB, &s_vec[0], lane));
            if (lane == 0) astore_f(xB + b, ((float*)s_x4)[b] + acc);
        }
        // ---- B2 (prefetch fvw quarter) ----
        bar_arrive(ctr, b);
        __builtin_amdgcn_sched_barrier(0);
        Row rFV;
        row_load(rFV, ffn_vw + (size_t)i * DD * FF + (size_t)b * FF + (size_t)w * 1024, lane);
        row_pin(rFV);
        bar_sync(ctr, rel, ++ev, b);

        // ================= stage C: LN2 + chan-mix + fkw/frw dots ===========
        cload(xv, xB + 4 * t); cwait1(xv);
        s_x4[t] = xv;
        n = ln_vec(xv, ln2_w + oD, ln2_b + oD, scr, t);
        if (b < 256 && t == b) {            // new_st[0] = xn2
            float* p = sto + 4 * b;
            p[0] = n[0]; p[1] = n[1]; p[2] = n[2]; p[3] = n[3];
        }
        {
            v4f sf = ((const v4f*)st)[t];
            s_mix[0][t] = mixv(n, sf, ((const v4f*)(ffn_tmk + oD))[t]);
            s_mix[1][t] = mixv(n, sf, ((const v4f*)(ffn_tmr + oD))[t]);
        }
        __syncthreads();
        {
            float acc = wave_sum(row_dot(rFK, &s_mix[0][0], lane));
            if (lane == 0) { float rl = fmaxf(acc, 0.f); astore_f(k2 + 4 * b + w, rl * rl); }
        }
        {
            float p = wave_sum(dotv(fr4, s_mix[1][w * 64 + lane]));
            if (lane == 0) s_red[w] = p;    // frw quarter partials
        }
        // ---- B3 (prefetch next-layer k/v/r rows, waves 0-2) ----
        bar_arrive(ctr, b);
        __builtin_amdgcn_sched_barrier(0);
        if (i + 1 < LL && w < 3)
            row_load(rAB, (w == 0 ? att_kw : w == 1 ? att_vw : att_rw)
                          + (size_t)(i + 1) * DD * DD + (size_t)b * DD, lane);
        row_pin(rAB);
        bar_sync(ctr, rel, ++ev, b);

        // ================= stage D: fvw dot + gated residual + rescale ======
        {
            v4f q0, q1, q2, q3;
            const float* kq = k2 + w * 1024;
            cload(q0, kq + lane * 4);
            cload(q1, kq + (lane + 64) * 4);
            cload(q2, kq + (lane + 128) * 4);
            cload(q3, kq + (lane + 192) * 4);
            cwait4(q0, q1, q2, q3);
            float acc = dotv(rFV.a, q0) + dotv(rFV.b, q1) + dotv(rFV.c, q2) + dotv(rFV.d, q3);
            acc = wave_sum(acc);
            if (lane == 0) s_red[4 + w] = acc;
        }
        __syncthreads();
        if (t == 0) {
            float r2 = 1.0f / (1.0f + expf(-(s_red[0] + s_red[1] + s_red[2] + s_red[3])));
            float dsum = s_red[4] + s_red[5] + s_red[6] + s_red[7];
            astore_f(xD + b, (((float*)s_x4)[b] + r2 * dsum) * scale);
        }
        // ---- B4 (prefetch next-layer ow row, wave 3) ----
        bar_arrive(ctr, b);
        __builtin_amdgcn_sched_barrier(0);
        if (i + 1 < LL && w == 3)
            row_load(rAB, att_ow + (size_t)(i + 1) * DD * DD + (size_t)b * DD, lane);
        row_pin(rAB);
        bar_sync(ctr, rel, ++ev, b);
    }

    // ================= head: LN_out + 50277x1024 GEMV ======================
    v4f xh;
    cload(xh, xD + 4 * t); cwait1(xh);
    v4f nh = ln_vec(xh, out_ln_w, out_ln_b, scr, t);
    s_vec[t] = nh;
    __syncthreads();
    for (int j = 0; j < 13; ++j) {
        int row = j * 4096 + 4 * b + w;
        if (row < VV) {
            Row rh;
            row_load(rh, head_w + (size_t)row * DD, lane);
            float acc = wave_sum(row_dot(rh, &s_vec[0], lane));
            if (lane == 0) logits[row] = acc;
        }
    }
}

// ---------------- launch ----------------

extern "C" void kernel_launch(void* const* d_in, const int* in_sizes, int n_in,
                              void* d_out, int out_size, void* d_ws, size_t ws_size,
                              hipStream_t stream) {
    const float* token_embd = (const float*)d_in[0];
    const float* state      = (const float*)d_in[1];
    const float* emb_ln_w   = (const float*)d_in[2];
    const float* emb_ln_b   = (const float*)d_in[3];
    const float* ln1_w      = (const float*)d_in[4];
    const float* ln1_b      = (const float*)d_in[5];
    const float* ln2_w      = (const float*)d_in[6];
    const float* ln2_b      = (const float*)d_in[7];
    const float* att_tmk    = (const float*)d_in[8];
    const float* att_tmv    = (const float*)d_in[9];
    const float* att_tmr    = (const float*)d_in[10];
    const float* att_tf     = (const float*)d_in[11];
    const float* att_td     = (const float*)d_in[12];
    const float* att_kw     = (const float*)d_in[13];
    const float* att_vw     = (const float*)d_in[14];
    const float* att_rw     = (const float*)d_in[15];
    const float* att_ow     = (const float*)d_in[16];
    const float* ffn_tmk    = (const float*)d_in[17];
    const float* ffn_tmr    = (const float*)d_in[18];
    const float* ffn_kw     = (const float*)d_in[19];
    const float* ffn_vw     = (const float*)d_in[20];
    const float* ffn_rw     = (const float*)d_in[21];
    const float* out_ln_w   = (const float*)d_in[22];
    const float* out_ln_b   = (const float*)d_in[23];
    const float* head_w     = (const float*)d_in[24];

    float* logits = (float*)d_out;
    float* st_out_base = (float*)d_out + VV;

    float* ws = (float*)d_ws;
    u32* syncm = (u32*)(ws + 9216);     // 32*32 ctr + 8*32 rel = 1280 u32

    hipMemsetAsync(syncm, 0, 1280 * sizeof(u32), stream);

    rwkv_all<<<NB, 256, 0, stream>>>(
        token_embd, state, emb_ln_w, emb_ln_b, ln1_w, ln1_b, ln2_w, ln2_b,
        att_tmk, att_tmv, att_tmr, att_tf, att_td,
        att_kw, att_vw, att_rw, att_ow,
        ffn_tmk, ffn_tmr, ffn_kw, ffn_vw, ffn_rw,
        out_ln_w, out_ln_b, head_w,
        logits, st_out_base, ws, syncm);
}